// Round 7
// baseline (533.826 us; speedup 1.0000x reference)
//
#include <hip/hip_runtime.h>
#include <math.h>

#define H 512
#define W 512
#define S (H*W)            // 262144 points per plane
#define BS 16
#define CH 3
#define WCS ((H-1)*W)      // weights_col per-batch stride (511*512)
#define WRS (H*(W-1))      // weights_row per-batch stride (512*511)
#define WRROW (W-1)        // weights_row row stride (511)
#define STRIP 8            // interior rows per block
#define EXTR (STRIP + 2)   // extended rows for step-1 (halo 1)
#define LROW 520           // LDS row stride (floats); data cols 4..515

// Fused 2-step Chebyshev-node Richardson, per-plane blocks (LDS 20.8 KB ->
// 7 blocks/CU). Step 1: 2 threads/column march 5 extended rows each with a
// 3-row register window (x row-loads 1.75x instead of 3x). Step 2: 8 interior
// rows from LDS -> global. 1D grid ordered idx = c*1024 + batch*64 + strip so
// the 3 channel-blocks of one (batch,strip) share idx%8 -> same XCD -> the
// per-batch weight lines are fetched into that XCD's L2 once, reused 3x.
__global__ void __launch_bounds__(256)
cheb2(const float* __restrict__ XS, float* __restrict__ XD,
      const float* __restrict__ Bp, const float* __restrict__ WC,
      const float* __restrict__ WR, float ta, float tb)
{
  __shared__ float x1[EXTR][LROW];   // 20800 B
  const int blk = (int)blockIdx.x;
  const int c   = blk >> 10;         // channel 0..2
  const int rem = blk & 1023;
  const int bb  = rem >> 6;          // batch 0..15
  const int st  = rem & 63;          // strip 0..63
  const int j   = bb * CH + c;       // plane
  const int y0  = st * STRIP;
  const int tid = (int)threadIdx.x;

  const float* xp  = XS + (size_t)j * S;
  const float* bp  = Bp + (size_t)j * S;
  const float* wcb = WC + (size_t)bb * WCS;
  const float* wrb = WR + (size_t)bb * WRS;
  const float4 z4 = make_float4(0.f, 0.f, 0.f, 0.f);

  // ---- step 1: vertical march, 5 ext rows per thread -> LDS ----
  {
    const int c4 = (tid & 127) << 2;     // column 0,4,...,508
    const int h  = tid >> 7;             // 0: ext rows 0..4, 1: rows 5..9
    const int ys = y0 - 1 + 5 * h;       // y of first computed ext row

    float4 xm = (ys - 1 >= 0 && ys - 1 < H)
                  ? *(const float4*)(xp + (ys - 1) * W + c4) : z4;
    float4 xc = (ys >= 0 && ys < H)
                  ? *(const float4*)(xp + ys * W + c4) : z4;
#pragma unroll
    for (int k = 0; k < 5; ++k) {
      const int y  = ys + k;
      const int rh = 5 * h + k;
      const float4 xq = (y + 1 >= 0 && y + 1 < H)
                          ? *(const float4*)(xp + (y + 1) * W + c4) : z4;
      float4 o = z4;
      if (y >= 0 && y < H) {
        const int t = y * W + c4;
        const float4 wu = (y > 0)     ? *(const float4*)(wcb + t - W) : z4;
        const float4 wd = (y < H - 1) ? *(const float4*)(wcb + t)     : z4;
        const float* wrow = wrb + (size_t)y * WRROW;
        const float wl0 = (c4 > 0) ? wrow[c4 - 1] : 0.f;
        const float w0 = wrow[c4], w1 = wrow[c4 + 1], w2 = wrow[c4 + 2];
        const float w3 = (c4 + 3 < W - 1) ? wrow[c4 + 3] : 0.f;
        const float4 wl = make_float4(wl0, w0, w1, w2);
        const float4 wr = make_float4(w0, w1, w2, w3);
        const float xlm = (c4 > 0)     ? xp[t - 1] : 0.f;
        const float xrp = (c4 + 4 < W) ? xp[t + 4] : 0.f;
        const float4 xl = make_float4(xlm, xc.x, xc.y, xc.z);
        const float4 xr = make_float4(xc.y, xc.z, xc.w, xrp);
        const float4 bv = *(const float4*)(bp + t);
#define ELEM(f) {                                                        \
          const float kv = 1.f + wu.f + wd.f + wl.f + wr.f;              \
          const float av = kv * xc.f - wu.f * xm.f - wd.f * xq.f         \
                           - wl.f * xl.f - wr.f * xr.f;                  \
          o.f = xc.f + ta * (bv.f - av); }
        ELEM(x) ELEM(y) ELEM(z) ELEM(w)
#undef ELEM
      }
      *(float4*)&x1[rh][4 + c4] = o;
      if (c4 == 0)   x1[rh][3]   = 0.f;
      if (c4 == 508) x1[rh][516] = 0.f;
      xm = xc; xc = xq;
    }
  }
  __syncthreads();

  // ---- step 2: 8 interior rows from LDS -> global ----
  for (int it = tid; it < STRIP * 128; it += 256) {
    const int rr = it >> 7;              // 0..7
    const int c4 = (it & 127) << 2;
    const int y  = y0 + rr;
    const int l  = rr + 1;
    const int t  = y * W + c4;

    const float4 xc = *(const float4*)&x1[l][4 + c4];
    const float4 xu = *(const float4*)&x1[l - 1][4 + c4];
    const float4 xd = *(const float4*)&x1[l + 1][4 + c4];
    const float4 l4 = *(const float4*)&x1[l][c4];      // aligned; use .w
    const float4 r4 = *(const float4*)&x1[l][8 + c4];  // aligned; use .x
    const float4 xl = make_float4(l4.w, xc.x, xc.y, xc.z);
    const float4 xr = make_float4(xc.y, xc.z, xc.w, r4.x);

    const float4 bv = *(const float4*)(bp + t);
    const float4 wu = (y > 0)     ? *(const float4*)(wcb + t - W) : z4;
    const float4 wd = (y < H - 1) ? *(const float4*)(wcb + t)     : z4;
    const float* wrow = wrb + (size_t)y * WRROW;
    const float wl0 = (c4 > 0) ? wrow[c4 - 1] : 0.f;
    const float w0 = wrow[c4], w1 = wrow[c4 + 1], w2 = wrow[c4 + 2];
    const float w3 = (c4 + 3 < W - 1) ? wrow[c4 + 3] : 0.f;
    const float4 wl = make_float4(wl0, w0, w1, w2);
    const float4 wr = make_float4(w0, w1, w2, w3);

    float4 out;
#define ELEM(f) {                                                        \
      const float kv = 1.f + wu.f + wd.f + wl.f + wr.f;                  \
      const float av = kv * xc.f - wu.f * xu.f - wd.f * xd.f             \
                       - wl.f * xl.f - wr.f * xr.f;                      \
      out.f = xc.f + tb * (bv.f - av); }
    ELEM(x) ELEM(y) ELEM(z) ELEM(w)
#undef ELEM
    *(float4*)(XD + (size_t)j * S + t) = out;
  }
}

extern "C" void kernel_launch(void* const* d_in, const int* in_sizes, int n_in,
                              void* d_out, int out_size, void* d_ws, size_t ws_size,
                              hipStream_t stream) {
  const float* Bp = (const float*)d_in[0];
  const float* WC = (const float*)d_in[1];
  const float* WR = (const float*)d_in[2];
  float* Xout = (float*)d_out;
  float* bufA = (float*)d_ws;          // 50 MB ping buffer

  // 10 Chebyshev nodes on [1,9]; residual poly max 1/T_10(1.25) ~= 2.0e-3.
  // Conjugate pairs (i, 11-i), larger-lambda node first within each pair;
  // every pair-product <= ~0.9 on [1,9] -> any pair order is fp32-stable.
  const int ord[10] = {1,10, 2,9, 3,8, 4,7, 5,6};
  float tau[10];
  for (int i = 0; i < 10; ++i) {
    const double lam = 5.0 + 4.0 * cos(M_PI * (2.0 * ord[i] - 1.0) / 20.0);
    tau[i] = (float)(1.0 / lam);
  }

  dim3 grid(CH * BS * (H / STRIP)), block(256);   // 3072 blocks, 1D
  const float* src = Bp;               // x_0 = B
  for (int i = 0; i < 5; ++i) {
    float* dst = (i & 1) ? bufA : Xout;            // i=4 -> Xout holds x_10
    cheb2<<<grid, block, 0, stream>>>(src, dst, Bp, WC, WR,
                                      tau[2 * i], tau[2 * i + 1]);
    src = dst;
  }
}

// Round 8
// 401.579 us; speedup vs baseline: 1.3293x; 1.3293x over previous
//
#include <hip/hip_runtime.h>
#include <hip/hip_fp16.h>
#include <math.h>

#define H 512
#define W 512
#define S (H*W)            // 262144 points per plane
#define BS 16
#define CH 3
#define NP (BS*CH)         // 48 planes
#define WCS ((H-1)*W)      // weights_col per-batch stride (261632)
#define WRS (H*(W-1))      // weights_row per-batch stride (261632)
#define WRROW (W-1)        // weights_row row stride (511)
#define STRIP 8            // interior rows per block
#define EXTR (STRIP + 2)   // extended rows for step-1
#define LROW 520           // LDS row stride (floats); data cols 4..515
#define WSLICE (WCS/64)    // 4088 weight elements per strip-block (both wc,wr)

// ---- fp16 <-> fp32 helpers (single 8B load/store for 4 halfs) ----
__device__ __forceinline__ float4 ld4h(const __half* p) {
  const float2 raw = *(const float2*)p;
  const __half2 h0 = *(const __half2*)&raw.x;
  const __half2 h1 = *(const __half2*)&raw.y;
  const float2 a = __half22float2(h0), b = __half22float2(h1);
  return make_float4(a.x, a.y, b.x, b.y);
}
__device__ __forceinline__ void st4h(__half* p, float4 v) {
  const __half2 h0 = __floats2half2_rn(v.x, v.y);
  const __half2 h1 = __floats2half2_rn(v.z, v.w);
  float2 raw;
  raw.x = *(const float*)&h0; raw.y = *(const float*)&h1;
  *(float2*)p = raw;
}

// Prologue: one Richardson step x_a = B + tau*(B - A*B) (fp32 in, fp16 out)
// + convert weights fp32 -> fp16 (channel-0 blocks only).
__global__ void __launch_bounds__(256)
cheb_pro(const float* __restrict__ Bp, const float* __restrict__ WC,
         const float* __restrict__ WR, __half* __restrict__ XA,
         __half* __restrict__ WC16, __half* __restrict__ WR16, float tau)
{
  const int j  = blockIdx.y;           // plane 0..47
  const int bb = j / CH;
  const int st = blockIdx.x;           // strip 0..63
  const int y0 = st * STRIP;
  const int tid = (int)threadIdx.x;
  const float* bp  = Bp + (size_t)j * S;
  const float* wcb = WC + (size_t)bb * WCS;
  const float* wrb = WR + (size_t)bb * WRS;
  const float4 z4 = make_float4(0.f, 0.f, 0.f, 0.f);

  for (int it = tid; it < STRIP * 128; it += 256) {
    const int rr = it >> 7;
    const int c4 = (it & 127) << 2;
    const int y  = y0 + rr;
    const int t  = y * W + c4;
    const float4 xc = *(const float4*)(bp + t);
    const float4 xu = (y > 0)     ? *(const float4*)(bp + t - W) : z4;
    const float4 xd = (y < H - 1) ? *(const float4*)(bp + t + W) : z4;
    const float4 wu = (y > 0)     ? *(const float4*)(wcb + t - W) : z4;
    const float4 wd = (y < H - 1) ? *(const float4*)(wcb + t)     : z4;
    const float* wrow = wrb + (size_t)y * WRROW;
    const float wl0 = (c4 > 0) ? wrow[c4 - 1] : 0.f;
    const float w0 = wrow[c4], w1 = wrow[c4 + 1], w2 = wrow[c4 + 2];
    const float w3 = (c4 + 3 < W - 1) ? wrow[c4 + 3] : 0.f;
    const float4 wl = make_float4(wl0, w0, w1, w2);
    const float4 wr = make_float4(w0, w1, w2, w3);
    const float xlm = (c4 > 0)     ? bp[t - 1] : 0.f;
    const float xrp = (c4 + 4 < W) ? bp[t + 4] : 0.f;
    const float4 xl = make_float4(xlm, xc.x, xc.y, xc.z);
    const float4 xr = make_float4(xc.y, xc.z, xc.w, xrp);
    float4 o;
#define ELEM(f) {                                                        \
      const float kv = 1.f + wu.f + wd.f + wl.f + wr.f;                  \
      const float av = kv * xc.f - wu.f * xu.f - wd.f * xd.f             \
                       - wl.f * xl.f - wr.f * xr.f;                      \
      o.f = xc.f + tau * (xc.f - av); }
    ELEM(x) ELEM(y) ELEM(z) ELEM(w)
#undef ELEM
    st4h(XA + (size_t)j * S + t, o);
  }

  if (j % CH == 0) {   // one block-set per batch converts this strip's slices
    const size_t boff = (size_t)bb * WCS;   // == bb*WRS
    const int base = st * WSLICE;
    for (int it = tid; it < WSLICE / 4; it += 256) {       // 1022 float4s
      const float4 a = *(const float4*)(wcb + base + it * 4);
      st4h(WC16 + boff + base + it * 4, a);
      const float4 b = *(const float4*)(wrb + base + it * 4);
      st4h(WR16 + boff + base + it * 4, b);
    }
  }
}

// Fused 2-step pair: x1 = x + ta*(b - A x) (march -> LDS),
//                    x2 = x1 + tb*(b - A x1) (LDS -> global, fp16 or fp32).
template <bool FINAL>
__global__ void __launch_bounds__(256)
cheb2(const __half* __restrict__ XS, __half* __restrict__ XDh,
      float* __restrict__ XDf, const float* __restrict__ Bp,
      const __half* __restrict__ WC16, const __half* __restrict__ WR16,
      float ta, float tb)
{
  __shared__ float x1[EXTR][LROW];   // 20800 B -> 7 blocks/CU
  const int j  = blockIdx.y;         // plane 0..47
  const int bb = j / CH;
  const int y0 = (int)blockIdx.x * STRIP;
  const int tid = (int)threadIdx.x;

  const __half* xp  = XS + (size_t)j * S;
  const float*  bp  = Bp + (size_t)j * S;
  const __half* wcb = WC16 + (size_t)bb * WCS;
  const __half* wrb = WR16 + (size_t)bb * WRS;
  const float4 z4 = make_float4(0.f, 0.f, 0.f, 0.f);

  // ---- step 1: vertical march, 5 ext rows per thread -> LDS ----
  {
    const int c4 = (tid & 127) << 2;     // column 0,4,...,508
    const int h  = tid >> 7;             // 0: ext rows 0..4, 1: rows 5..9
    const int ys = y0 - 1 + 5 * h;

    float4 xm = (ys - 1 >= 0 && ys - 1 < H) ? ld4h(xp + (ys - 1) * W + c4) : z4;
    float4 xc = (ys >= 0 && ys < H)         ? ld4h(xp + ys * W + c4)       : z4;
#pragma unroll
    for (int k = 0; k < 5; ++k) {
      const int y  = ys + k;
      const int rh = 5 * h + k;
      const float4 xq = (y + 1 >= 0 && y + 1 < H) ? ld4h(xp + (y + 1) * W + c4)
                                                  : z4;
      float4 o = z4;
      if (y >= 0 && y < H) {
        const int t = y * W + c4;
        const float4 wu = (y > 0)     ? ld4h(wcb + t - W) : z4;
        const float4 wd = (y < H - 1) ? ld4h(wcb + t)     : z4;
        const __half* wrow = wrb + (size_t)y * WRROW;
        const float wl0 = (c4 > 0) ? __half2float(wrow[c4 - 1]) : 0.f;
        const float w0 = __half2float(wrow[c4]);
        const float w1 = __half2float(wrow[c4 + 1]);
        const float w2 = __half2float(wrow[c4 + 2]);
        const float w3 = (c4 + 3 < W - 1) ? __half2float(wrow[c4 + 3]) : 0.f;
        const float4 wl = make_float4(wl0, w0, w1, w2);
        const float4 wr = make_float4(w0, w1, w2, w3);
        const float xlm = (c4 > 0)     ? __half2float(xp[t - 1]) : 0.f;
        const float xrp = (c4 + 4 < W) ? __half2float(xp[t + 4]) : 0.f;
        const float4 xl = make_float4(xlm, xc.x, xc.y, xc.z);
        const float4 xr = make_float4(xc.y, xc.z, xc.w, xrp);
        const float4 bv = *(const float4*)(bp + t);
#define ELEM(f) {                                                        \
          const float kv = 1.f + wu.f + wd.f + wl.f + wr.f;              \
          const float av = kv * xc.f - wu.f * xm.f - wd.f * xq.f         \
                           - wl.f * xl.f - wr.f * xr.f;                  \
          o.f = xc.f + ta * (bv.f - av); }
        ELEM(x) ELEM(y) ELEM(z) ELEM(w)
#undef ELEM
      }
      *(float4*)&x1[rh][4 + c4] = o;
      if (c4 == 0)   x1[rh][3]   = 0.f;
      if (c4 == 508) x1[rh][516] = 0.f;
      xm = xc; xc = xq;
    }
  }
  __syncthreads();

  // ---- step 2: 8 interior rows from LDS -> global ----
  for (int it = tid; it < STRIP * 128; it += 256) {
    const int rr = it >> 7;
    const int c4 = (it & 127) << 2;
    const int y  = y0 + rr;
    const int l  = rr + 1;
    const int t  = y * W + c4;

    const float4 xc = *(const float4*)&x1[l][4 + c4];
    const float4 xu = *(const float4*)&x1[l - 1][4 + c4];
    const float4 xd = *(const float4*)&x1[l + 1][4 + c4];
    const float4 l4 = *(const float4*)&x1[l][c4];      // aligned; use .w
    const float4 r4 = *(const float4*)&x1[l][8 + c4];  // aligned; use .x
    const float4 xl = make_float4(l4.w, xc.x, xc.y, xc.z);
    const float4 xr = make_float4(xc.y, xc.z, xc.w, r4.x);

    const float4 bv = *(const float4*)(bp + t);
    const float4 wu = (y > 0)     ? ld4h(wcb + t - W) : z4;
    const float4 wd = (y < H - 1) ? ld4h(wcb + t)     : z4;
    const __half* wrow = wrb + (size_t)y * WRROW;
    const float wl0 = (c4 > 0) ? __half2float(wrow[c4 - 1]) : 0.f;
    const float w0 = __half2float(wrow[c4]);
    const float w1 = __half2float(wrow[c4 + 1]);
    const float w2 = __half2float(wrow[c4 + 2]);
    const float w3 = (c4 + 3 < W - 1) ? __half2float(wrow[c4 + 3]) : 0.f;
    const float4 wl = make_float4(wl0, w0, w1, w2);
    const float4 wr = make_float4(w0, w1, w2, w3);

    float4 out;
#define ELEM(f) {                                                        \
      const float kv = 1.f + wu.f + wd.f + wl.f + wr.f;                  \
      const float av = kv * xc.f - wu.f * xu.f - wd.f * xd.f             \
                       - wl.f * xl.f - wr.f * xr.f;                      \
      out.f = xc.f + tb * (bv.f - av); }
    ELEM(x) ELEM(y) ELEM(z) ELEM(w)
#undef ELEM
    if (FINAL) *(float4*)(XDf + (size_t)j * S + t) = out;
    else       st4h(XDh + (size_t)j * S + t, out);
  }
}

extern "C" void kernel_launch(void* const* d_in, const int* in_sizes, int n_in,
                              void* d_out, int out_size, void* d_ws, size_t ws_size,
                              hipStream_t stream) {
  const float* Bp = (const float*)d_in[0];
  const float* WC = (const float*)d_in[1];
  const float* WR = (const float*)d_in[2];
  float* Xout = (float*)d_out;
  __half* xA   = (__half*)d_ws;                 // NP*S halfs (25.2 MB)
  __half* xB   = xA + (size_t)NP * S;           // 25.2 MB
  __half* wc16 = xB + (size_t)NP * S;           // BS*WCS halfs (8.4 MB)
  __half* wr16 = wc16 + (size_t)BS * WCS;       // 8.4 MB

  // K=11 Chebyshev nodes on [1,9]: lam_i = 5 + 4 cos((2i-1)pi/22).
  // Prologue applies the middle node i=6 (lam=5); then conjugate pairs
  // (1,11)(2,10)(3,9)(4,8)(5,7), larger-lambda node first.
  // Residual poly max = 2/(2^11 + 2^-11) ~= 9.8e-4.
  auto lam = [](int i) { return 5.0 + 4.0 * cos(M_PI * (2.0 * i - 1.0) / 22.0); };
  const float tauMid = (float)(1.0 / lam(6));
  const int pa[5] = {1, 2, 3, 4, 5}, pb[5] = {11, 10, 9, 8, 7};

  dim3 grid(H / STRIP, NP), block(256);
  cheb_pro<<<grid, block, 0, stream>>>(Bp, WC, WR, xA, wc16, wr16, tauMid);

  const __half* src = xA;
  __half* dst = xB;
  for (int i = 0; i < 5; ++i) {
    const float ta = (float)(1.0 / lam(pa[i]));
    const float tb = (float)(1.0 / lam(pb[i]));
    if (i < 4) {
      cheb2<false><<<grid, block, 0, stream>>>(src, dst, nullptr, Bp,
                                               wc16, wr16, ta, tb);
      const __half* t = src; src = dst; dst = (__half*)t;
    } else {
      cheb2<true><<<grid, block, 0, stream>>>(src, nullptr, Xout, Bp,
                                              wc16, wr16, ta, tb);
    }
  }
}

// Round 9
// 356.590 us; speedup vs baseline: 1.4970x; 1.1262x over previous
//
#include <hip/hip_runtime.h>
#include <hip/hip_fp16.h>
#include <math.h>

#define H 512
#define W 512
#define S (H*W)            // 262144 px per plane
#define BS 16
#define CH 3
#define NP (BS*CH)         // 48 planes
#define WCS ((H-1)*W)      // col-weight per-batch stride in halves (511 rows x 512)
#define WRS (H*(W-1))      // row-weight SOURCE per-batch stride (512 x 511 fp32)
#define WRSP (H*W)         // row-weight PADDED per-batch stride (512 x 512 halves)
#define STRIP 8            // interior rows per block
#define NEXT 10            // extended rows (halo 1)

typedef unsigned int   uint_t;
typedef unsigned short ush;

struct F8 { float f[8]; };

__device__ __forceinline__ F8 unpk(uint4 r) {
  F8 o;
  float2 a = __half22float2(*(__half2*)&r.x); o.f[0]=a.x; o.f[1]=a.y;
  float2 b = __half22float2(*(__half2*)&r.y); o.f[2]=b.x; o.f[3]=b.y;
  float2 c = __half22float2(*(__half2*)&r.z); o.f[4]=c.x; o.f[5]=c.y;
  float2 d = __half22float2(*(__half2*)&r.w); o.f[6]=d.x; o.f[7]=d.y;
  return o;
}
__device__ __forceinline__ uint_t pk2(float a, float b) {
  __half2 h = __floats2half2_rn(a, b); return *(uint_t*)&h;
}
__device__ __forceinline__ uint4 pk8(const float* f) {
  return make_uint4(pk2(f[0],f[1]), pk2(f[2],f[3]), pk2(f[4],f[5]), pk2(f[6],f[7]));
}
__device__ __forceinline__ float hi_h(uint_t u){ return __half22float2(*(__half2*)&u).y; }
__device__ __forceinline__ float lo_h(uint_t u){ return __half22float2(*(__half2*)&u).x; }

// One Richardson step on one full row (8 px/lane, wave = 512-px row).
// Horizontal neighbors (x and left row-weight) via intra-wave shuffles:
// lane0 left = 0 (domain edge), lane63 right = 0 (pad col 511 = 0).
__device__ __forceinline__ void row_cheb(const uint4 xcr, const uint4 xur,
    const uint4 xdr, const uint4 wur, const uint4 wdr, const uint4 wrr,
    const uint4 br, const float tau, const int lane, float o[8])
{
  const F8 x = unpk(xcr), xu = unpk(xur), xd = unpk(xdr),
           wu = unpk(wur), wd = unpk(wdr), w = unpk(wrr), b = unpk(br);
  const uint_t ux = (uint_t)__shfl_up((int)xcr.w, 1);
  const float xl0 = lane ? hi_h(ux) : 0.f;
  const uint_t dx = (uint_t)__shfl_down((int)xcr.x, 1);
  const float xr7 = (lane < 63) ? lo_h(dx) : 0.f;
  const uint_t uw = (uint_t)__shfl_up((int)wrr.w, 1);
  const float wlm = lane ? hi_h(uw) : 0.f;
#pragma unroll
  for (int p = 0; p < 8; ++p) {
    const float wl = p ? w.f[p-1] : wlm;
    const float wr = w.f[p];
    const float xl = p ? x.f[p-1] : xl0;
    const float xr = (p < 7) ? x.f[p+1] : xr7;
    const float kv = 1.f + wu.f[p] + wd.f[p] + wl + wr;
    const float av = kv * x.f[p] - wu.f[p]*xu.f[p] - wd.f[p]*xd.f[p]
                     - wl*xl - wr*xr;
    o[p] = x.f[p] + tau * (b.f[p] - av);
  }
}

#define LDP(ptr, y) (((unsigned)(y) < H)   ? *(const uint4*)((ptr) + (size_t)(y)*W + lane*8) : zz)
#define LDC(ptr, y) (((unsigned)(y) < H-1) ? *(const uint4*)((ptr) + (size_t)(y)*W + lane*8) : zz)

// Fused pair: x1 = x + ta*(b - A x) on 10 ext rows -> LDS (x1 + both weight
// rows stashed); x2 = x1 + tb*(b - A x1) on 8 interior rows -> global.
// All global accesses are aligned b128; zero scalar loads.
template <bool FINAL>
__global__ void __launch_bounds__(256)
cheb_pair(const ush* __restrict__ XS, ush* __restrict__ XD,
          float* __restrict__ XF, const ush* __restrict__ B16,
          const ush* __restrict__ WC16, const ush* __restrict__ WR16,
          float ta, float tb)
{
  __shared__ __align__(16) ush x1h[NEXT][W];   // 10 KiB
  __shared__ __align__(16) ush wcl[NEXT][W];   // 10 KiB  (wcl[m] = wc row y0-1+m)
  __shared__ __align__(16) ush wrl[NEXT][W];   // 10 KiB  (wrl[m] = wr row y0-1+m)
  const int j  = blockIdx.y;          // plane 0..47
  const int bb = j / CH;              // batch
  const int y0 = (int)blockIdx.x * STRIP;
  const int tid = (int)threadIdx.x;
  const int wv = tid >> 6, lane = tid & 63;
  const uint4 zz = make_uint4(0,0,0,0);

  const ush* xp = XS  + (size_t)j * S;
  const ush* bp = B16 + (size_t)j * S;
  const ush* wc = WC16 + (size_t)bb * WCS;
  const ush* wr = WR16 + (size_t)bb * WRSP;

  // ---- step 1: ext rows rh = wv + 4k (independent, fully unrolled) ----
#pragma unroll
  for (int k = 0; k < 3; ++k) {
    const int rh = wv + 4*k;
    if (rh < NEXT) {                       // wave-uniform
      const int y = y0 - 1 + rh;
      const uint4 xm = LDP(xp, y-1), xc = LDP(xp, y), xq = LDP(xp, y+1);
      const uint4 wpv = LDC(wc, y-1), wcur = LDC(wc, y);
      const uint4 wrow = LDP(wr, y);
      float o[8] = {0.f,0.f,0.f,0.f,0.f,0.f,0.f,0.f};
      if ((unsigned)y < H) {               // wave-uniform
        const uint4 bv = *(const uint4*)(bp + (size_t)y*W + lane*8);
        row_cheb(xc, xm, xq, wpv, wcur, wrow, bv, ta, lane, o);
      }
      *(uint4*)&x1h[rh][lane*8] = pk8(o);
      *(uint4*)&wcl[rh][lane*8] = wcur;
      *(uint4*)&wrl[rh][lane*8] = wrow;
    }
  }
  __syncthreads();

  // ---- step 2: interior rows from LDS; only B-load + store hit global ----
#pragma unroll
  for (int k = 0; k < 2; ++k) {
    const int ri = wv*2 + k, l = ri + 1, y = y0 + ri;
    const uint4 xc = *(const uint4*)&x1h[l][lane*8];
    const uint4 xu = *(const uint4*)&x1h[l-1][lane*8];
    const uint4 xd = *(const uint4*)&x1h[l+1][lane*8];
    const uint4 wu = *(const uint4*)&wcl[l-1][lane*8];
    const uint4 wd = *(const uint4*)&wcl[l][lane*8];
    const uint4 wrow = *(const uint4*)&wrl[l][lane*8];
    const uint4 bv = *(const uint4*)(bp + (size_t)y*W + lane*8);
    float o[8];
    row_cheb(xc, xu, xd, wu, wd, wrow, bv, tb, lane, o);
    if (FINAL) {
      float* dst = XF + (size_t)j*S + (size_t)y*W + lane*8;
      *(float4*)dst       = make_float4(o[0],o[1],o[2],o[3]);
      *(float4*)(dst + 4) = make_float4(o[4],o[5],o[6],o[7]);
    } else {
      *(uint4*)(XD + (size_t)j*S + (size_t)y*W + lane*8) = pk8(o);
    }
  }
}

// Prologue: pure fp32 -> fp16 conversion. B and WC flat; WR repacked to
// stride-512 rows with col 511 = 0.
__global__ void __launch_bounds__(256)
convert(const float* __restrict__ B, const float* __restrict__ WCs,
        const float* __restrict__ WRs, ush* __restrict__ B16,
        ush* __restrict__ WC16, ush* __restrict__ WR16)
{
  const long long NB = (long long)NP * S / 4;    // 3,145,728 float4 units
  const long long NC = (long long)BS * WCS / 4;  // 1,046,528
  const long long NR = (long long)BS * H * (W/4);// 1,048,576 dst 4-col units
  const long long tot = NB + NC + NR;
  const long long stride = (long long)gridDim.x * blockDim.x;
  for (long long i = (long long)blockIdx.x * blockDim.x + threadIdx.x;
       i < tot; i += stride) {
    if (i < NB) {
      const float4 v = ((const float4*)B)[i];
      ((uint2*)B16)[i] = make_uint2(pk2(v.x,v.y), pk2(v.z,v.w));
    } else if (i < NB + NC) {
      const long long q = i - NB;
      const float4 v = ((const float4*)WCs)[q];
      ((uint2*)WC16)[q] = make_uint2(pk2(v.x,v.y), pk2(v.z,v.w));
    } else {
      const long long q = i - NB - NC;           // batch*65536 + y*128 + u
      const int b   = (int)(q >> 16);
      const int rem = (int)(q & 65535);
      const int y   = rem >> 7;
      const int c4  = (rem & 127) << 2;
      const float* s = WRs + (size_t)b * WRS + (size_t)y * (W-1) + c4;
      const float a0 = s[0], a1 = s[1], a2 = s[2];
      const float a3 = (c4 == 508) ? 0.f : s[3];
      ((uint2*)WR16)[q] = make_uint2(pk2(a0,a1), pk2(a2,a3));
    }
  }
}

extern "C" void kernel_launch(void* const* d_in, const int* in_sizes, int n_in,
                              void* d_out, int out_size, void* d_ws, size_t ws_size,
                              hipStream_t stream) {
  const float* Bp = (const float*)d_in[0];
  const float* WC = (const float*)d_in[1];
  const float* WR = (const float*)d_in[2];
  float* Xout = (float*)d_out;
  ush* B16  = (ush*)d_ws;                       // 25.2 MB (also x_0)
  ush* XA   = B16 + (size_t)NP * S;             // 25.2 MB
  ush* XB   = XA + (size_t)NP * S;              // 25.2 MB
  ush* WC16 = XB + (size_t)NP * S;              // 8.37 MB
  ush* WR16 = WC16 + (size_t)BS * WCS;          // 8.39 MB (padded)

  // 10 Chebyshev nodes on [1,9]; residual poly max 2/(2^10+2^-10) ~= 2e-3.
  // Conjugate pairs (i, 11-i), larger-lambda node first.
  auto lamf = [](int i) { return 5.0 + 4.0 * cos(M_PI * (2.0*i - 1.0) / 20.0); };
  const int pa[5] = {1, 2, 3, 4, 5}, pb[5] = {10, 9, 8, 7, 6};

  convert<<<2048, 256, 0, stream>>>(Bp, WC, WR, B16, WC16, WR16);

  dim3 grid(H / STRIP, NP), block(256);
  const ush* xsrc[5] = {B16, XA, XB, XA, XB};
  ush*       xdst[5] = {XA,  XB, XA, XB, nullptr};
  for (int i = 0; i < 5; ++i) {
    const float ta = (float)(1.0 / lamf(pa[i]));
    const float tb = (float)(1.0 / lamf(pb[i]));
    if (i < 4)
      cheb_pair<false><<<grid, block, 0, stream>>>(xsrc[i], xdst[i], nullptr,
                                                   B16, WC16, WR16, ta, tb);
    else
      cheb_pair<true><<<grid, block, 0, stream>>>(xsrc[i], nullptr, Xout,
                                                  B16, WC16, WR16, ta, tb);
  }
}